// Round 2
// baseline (577.957 us; speedup 1.0000x reference)
//
#include <hip/hip_runtime.h>
#include <hip/hip_bf16.h>
#include <cstddef>
#include <cstdint>

#define NREADS 65536
#define DDIM 128
#define BANKM 8
#define LN_EPS 1e-5f
#define QK_SCALE 0.08838834764831845f

typedef __bf16 bf16_t;
typedef bf16_t bf16x4 __attribute__((ext_vector_type(4)));
typedef bf16_t bf16x8 __attribute__((ext_vector_type(8)));
typedef float  f32x4  __attribute__((ext_vector_type(4)));

// ---------------- K0: fold weights ----------------
// A[c][d]  = sum_e Wq[e][c]*Wk[e][d]   (Qt = cur@A + c0; c0 = bq@Wk)
// W2[e][d] = sum_k Wo[e][k]*Wv[k][d]   (x = cur + p@W2^T + b2; b2 = Wo@bv + bo)
// bk is dropped: it adds Q.bk uniformly to all logits -> softmax-invariant.
// Stored: Atb[d][c] (bf16, transposed so GEMM1 B-frag k-runs are contiguous),
//         W2b[e][d] (bf16, natural layout: k=d contiguous for GEMM2 B-frags).
__global__ void fold_w(const float* __restrict__ Wq, const float* __restrict__ bq,
                       const float* __restrict__ Wk,
                       const float* __restrict__ Wv, const float* __restrict__ bv,
                       const float* __restrict__ Wo, const float* __restrict__ bo,
                       bf16_t* __restrict__ Atb, bf16_t* __restrict__ W2b,
                       float* __restrict__ c0, float* __restrict__ b2) {
  int i = blockIdx.x * 256 + threadIdx.x;   // 0..16383
  int d = i & 127;
  int c = i >> 7;                            // doubles as 'e' for W2
  float accA = 0.f, accW = 0.f;
  for (int e = 0; e < 128; ++e) {
    accA += Wq[e*128 + c] * Wk[e*128 + d];   // broadcast + coalesced
    accW += Wo[c*128 + e] * Wv[e*128 + d];
  }
  Atb[d*128 + c] = (bf16_t)accA;
  W2b[c*128 + d] = (bf16_t)accW;
  if (i < 128) {
    float s0 = 0.f, s1 = 0.f;
    for (int e = 0; e < 128; ++e) {
      s0 += bq[e] * Wk[e*128 + i];
      s1 += Wo[i*128 + e] * bv[e];
    }
    c0[i] = s0;
    b2[i] = s1 + bo[i];
  }
}

// ---------------- K1: Qt = cur @ A + c0  (bf16 MFMA) ----------------
// Block: 256 thr = 4 waves, 64 rows/block. LDS stride 132 bf16 (264 B) makes
// the 16-lane frag reads land on banks {2l,2l+1} -> conflict-free b64s.
// MFMA 16x16x32 operand layout: elem j <-> k = 4*(lane>>4) + (j&3) + 16*(j>>2).
__global__ __launch_bounds__(256) void gemm_qt(
    const float* __restrict__ cur, const bf16_t* __restrict__ Atb,
    const float* __restrict__ c0, bf16_t* __restrict__ Qtb) {
  __shared__ bf16_t At[128][132];
  __shared__ bf16_t Cu[64][132];
  const int t = threadIdx.x;
  const int r0 = blockIdx.x * 64;
  #pragma unroll
  for (int s0 = 0; s0 < 2048; s0 += 256) {         // stage A^T (16384 bf16)
    int s = s0 + t;
    int d = s >> 4, cc = (s & 15) * 8;
    bf16x8 v = *(const bf16x8*)(Atb + d*128 + cc);
    *(bf16x4*)&At[d][cc]     = __builtin_shufflevector(v, v, 0,1,2,3);
    *(bf16x4*)&At[d][cc + 4] = __builtin_shufflevector(v, v, 4,5,6,7);
  }
  #pragma unroll
  for (int s0 = 0; s0 < 2048; s0 += 256) {         // stage cur tile -> bf16
    int s = s0 + t;
    int r = s >> 5, cc = (s & 31) * 4;
    f32x4 v = *(const f32x4*)(cur + (size_t)(r0 + r)*128 + cc);
    bf16x4 b;
    b[0] = (bf16_t)v[0]; b[1] = (bf16_t)v[1]; b[2] = (bf16_t)v[2]; b[3] = (bf16_t)v[3];
    *(bf16x4*)&Cu[r][cc] = b;
  }
  __syncthreads();
  const int w = t >> 6, l = t & 63;
  const int lr = l & 15, lg = l >> 4;
  f32x4 acc[8] = {};
  #pragma unroll
  for (int ks = 0; ks < 4; ++ks) {
    const int kb = ks*32 + lg*4;
    bf16x4 alo = *(const bf16x4*)&Cu[w*16 + lr][kb];
    bf16x4 ahi = *(const bf16x4*)&Cu[w*16 + lr][kb + 16];
    bf16x8 a = __builtin_shufflevector(alo, ahi, 0,1,2,3,4,5,6,7);
    #pragma unroll
    for (int n = 0; n < 8; ++n) {
      bf16x4 blo = *(const bf16x4*)&At[n*16 + lr][kb];
      bf16x4 bhi = *(const bf16x4*)&At[n*16 + lr][kb + 16];
      bf16x8 bb = __builtin_shufflevector(blo, bhi, 0,1,2,3,4,5,6,7);
      acc[n] = __builtin_amdgcn_mfma_f32_16x16x32_bf16(a, bb, acc[n], 0, 0, 0);
    }
  }
  #pragma unroll
  for (int n = 0; n < 8; ++n) {                    // C/D: col=lane&15, row=4*(l>>4)+r
    const int col = n*16 + lr;
    const float cv = c0[col];
    #pragma unroll
    for (int r = 0; r < 4; ++r) {
      const int row = r0 + w*16 + lg*4 + r;
      Qtb[(size_t)row*128 + col] = (bf16_t)(acc[n][r] + cv);
    }
  }
}

// ---------------- K2: attention (1 wave per read) ----------------
// lane = m*8 + dg: owns cols [dg*16, dg*16+16) of slot m. Gather is a 4 KB
// contiguous row (lane l covers floats [16l,16l+16)). Reads its Qt row, writes
// p (bf16) IN PLACE over the Qt row (only this wave touches row n).
__global__ __launch_bounds__(256) void attn_k(
    const int* __restrict__ idx, const float* __restrict__ bank,
    bf16_t* __restrict__ Qp) {
  const int t = threadIdx.x;
  const int wv = t >> 6, l = t & 63;
  const int n = blockIdx.x * 4 + wv;
  const int m = l >> 3, dg = l & 7;
  const float* past = bank + (size_t)idx[n] * (BANKM*DDIM) + m*DDIM + dg*16;
  f32x4 p0 = *(const f32x4*)(past);
  f32x4 p1 = *(const f32x4*)(past + 4);
  f32x4 p2 = *(const f32x4*)(past + 8);
  f32x4 p3 = *(const f32x4*)(past + 12);
  const bf16_t* qrow = Qp + (size_t)n*128 + dg*16;
  bf16x8 q0 = *(const bf16x8*)(qrow);
  bf16x8 q1 = *(const bf16x8*)(qrow + 8);
  float pv[16], qv[16];
  #pragma unroll
  for (int i = 0; i < 4; ++i) {
    pv[i] = p0[i]; pv[4+i] = p1[i]; pv[8+i] = p2[i]; pv[12+i] = p3[i];
  }
  #pragma unroll
  for (int i = 0; i < 8; ++i) { qv[i] = (float)q0[i]; qv[8+i] = (float)q1[i]; }
  float s = 0.f;
  #pragma unroll
  for (int i = 0; i < 16; ++i) s = fmaf(qv[i], pv[i], s);
  s += __shfl_xor(s, 1);                 // reduce over dg (low 3 lane bits)
  s += __shfl_xor(s, 2);
  s += __shfl_xor(s, 4);
  const float logit = s * QK_SCALE;
  float mx = logit;                      // softmax over m (lane bits 3..5)
  mx = fmaxf(mx, __shfl_xor(mx, 8));
  mx = fmaxf(mx, __shfl_xor(mx, 16));
  mx = fmaxf(mx, __shfl_xor(mx, 32));
  const float ev = expf(logit - mx);
  float den = ev;
  den += __shfl_xor(den, 8);
  den += __shfl_xor(den, 16);
  den += __shfl_xor(den, 32);
  const float aw = ev / den;
  #pragma unroll
  for (int i = 0; i < 16; ++i) {         // p[d] = sum_m attn_m * past[m][d]
    float x = pv[i] * aw;
    x += __shfl_xor(x, 8);
    x += __shfl_xor(x, 16);
    x += __shfl_xor(x, 32);
    pv[i] = x;
  }
  if (m == 0) {
    bf16x8 o0, o1;
    #pragma unroll
    for (int i = 0; i < 8; ++i) { o0[i] = (bf16_t)pv[i]; o1[i] = (bf16_t)pv[8+i]; }
    bf16_t* prow = Qp + (size_t)n*128 + dg*16;
    *(bf16x8*)(prow)     = o0;
    *(bf16x8*)(prow + 8) = o1;
  }
}

// ---------------- K3: x = cur + p@W2^T + b2; LayerNorm -> out ----------------
__global__ __launch_bounds__(256) void gemm2_ln(
    const bf16_t* __restrict__ Pb, const bf16_t* __restrict__ W2b,
    const float* __restrict__ b2v, const float* __restrict__ cur,
    const float* __restrict__ gamma, const float* __restrict__ beta,
    float* __restrict__ out) {
  __shared__ bf16_t Wt[128][132];
  __shared__ bf16_t Pt[64][132];
  const int t = threadIdx.x;
  const int r0 = blockIdx.x * 64;
  #pragma unroll
  for (int s0 = 0; s0 < 2048; s0 += 256) {
    int s = s0 + t;
    int e = s >> 4, dd = (s & 15) * 8;
    bf16x8 v = *(const bf16x8*)(W2b + e*128 + dd);
    *(bf16x4*)&Wt[e][dd]     = __builtin_shufflevector(v, v, 0,1,2,3);
    *(bf16x4*)&Wt[e][dd + 4] = __builtin_shufflevector(v, v, 4,5,6,7);
  }
  #pragma unroll
  for (int s0 = 0; s0 < 1024; s0 += 256) {
    int s = s0 + t;
    int r = s >> 4, dd = (s & 15) * 8;
    bf16x8 v = *(const bf16x8*)(Pb + (size_t)(r0 + r)*128 + dd);
    *(bf16x4*)&Pt[r][dd]     = __builtin_shufflevector(v, v, 0,1,2,3);
    *(bf16x4*)&Pt[r][dd + 4] = __builtin_shufflevector(v, v, 4,5,6,7);
  }
  __syncthreads();
  const int w = t >> 6, l = t & 63;
  const int lr = l & 15, lg = l >> 4;
  f32x4 acc[8] = {};
  #pragma unroll
  for (int ks = 0; ks < 4; ++ks) {
    const int kb = ks*32 + lg*4;
    bf16x4 alo = *(const bf16x4*)&Pt[w*16 + lr][kb];
    bf16x4 ahi = *(const bf16x4*)&Pt[w*16 + lr][kb + 16];
    bf16x8 a = __builtin_shufflevector(alo, ahi, 0,1,2,3,4,5,6,7);
    #pragma unroll
    for (int n = 0; n < 8; ++n) {
      bf16x4 blo = *(const bf16x4*)&Wt[n*16 + lr][kb];
      bf16x4 bhi = *(const bf16x4*)&Wt[n*16 + lr][kb + 16];
      bf16x8 bb = __builtin_shufflevector(blo, bhi, 0,1,2,3,4,5,6,7);
      acc[n] = __builtin_amdgcn_mfma_f32_16x16x32_bf16(a, bb, acc[n], 0, 0, 0);
    }
  }
  float x[8][4];
  #pragma unroll
  for (int n = 0; n < 8; ++n) {
    const int col = n*16 + lr;
    const float bb2 = b2v[col];
    #pragma unroll
    for (int r = 0; r < 4; ++r) {
      const int row = r0 + w*16 + lg*4 + r;
      x[n][r] = acc[n][r] + bb2 + cur[(size_t)row*128 + col];
    }
  }
  // LN: row (4*lg + r) lives in the 16 contiguous lanes sharing lg -> xor 1,2,4,8
  #pragma unroll
  for (int r = 0; r < 4; ++r) {
    float s1 = 0.f, s2 = 0.f;
    #pragma unroll
    for (int n = 0; n < 8; ++n) { s1 += x[n][r]; s2 += x[n][r]*x[n][r]; }
    s1 += __shfl_xor(s1, 1); s2 += __shfl_xor(s2, 1);
    s1 += __shfl_xor(s1, 2); s2 += __shfl_xor(s2, 2);
    s1 += __shfl_xor(s1, 4); s2 += __shfl_xor(s2, 4);
    s1 += __shfl_xor(s1, 8); s2 += __shfl_xor(s2, 8);
    const float mean = s1 * (1.f/128.f);
    const float var  = s2 * (1.f/128.f) - mean*mean;
    const float rstd = rsqrtf(var + LN_EPS);
    const int row = r0 + w*16 + lg*4 + r;
    #pragma unroll
    for (int n = 0; n < 8; ++n) {
      const int col = n*16 + lr;
      out[(size_t)row*128 + col] = (x[n][r] - mean)*rstd*gamma[col] + beta[col];
    }
  }
}

extern "C" void kernel_launch(void* const* d_in, const int* in_sizes, int n_in,
                              void* d_out, int out_size, void* d_ws, size_t ws_size,
                              hipStream_t stream) {
  const int*   idx  = (const int*)d_in[0];
  const float* cur  = (const float*)d_in[1];
  const float* bank = (const float*)d_in[2];
  const float* Wq   = (const float*)d_in[3];
  const float* bq   = (const float*)d_in[4];
  const float* Wk   = (const float*)d_in[5];
  // d_in[6] = bk: softmax-invariant, intentionally unused
  const float* Wv   = (const float*)d_in[7];
  const float* bv   = (const float*)d_in[8];
  const float* Wo   = (const float*)d_in[9];
  const float* bo   = (const float*)d_in[10];
  const float* gm   = (const float*)d_in[11];
  const float* bt   = (const float*)d_in[12];
  float* out = (float*)d_out;

  char* ws = (char*)d_ws;
  bf16_t* Atb = (bf16_t*)(ws);                    // 32 KB
  bf16_t* W2b = (bf16_t*)(ws + 32768);            // 32 KB
  float*  c0  = (float*)(ws + 65536);             // 512 B
  float*  b2  = (float*)(ws + 65536 + 512);       // 512 B
  bf16_t* Qtb = (bf16_t*)(ws + (1 << 20));        // 16 MB (Qt, then p in-place)

  fold_w<<<64, 256, 0, stream>>>(Wq, bq, Wk, Wv, bv, Wo, bo, Atb, W2b, c0, b2);
  gemm_qt<<<NREADS/64, 256, 0, stream>>>(cur, Atb, c0, Qtb);
  attn_k<<<NREADS/4, 256, 0, stream>>>(idx, bank, Qtb);
  gemm2_ln<<<NREADS/64, 256, 0, stream>>>(Qtb, W2b, b2, cur, gm, bt, out);
}

// Round 7
// 570.491 us; speedup vs baseline: 1.0131x; 1.0131x over previous
//
#include <hip/hip_runtime.h>
#include <hip/hip_bf16.h>
#include <cstddef>
#include <cstdint>

#define NREADS 65536
#define DDIM 128
#define BANKM 8
#define LN_EPS 1e-5f
#define QK_SCALE 0.08838834764831845f

typedef __bf16 bf16_t;
typedef bf16_t bf16x4 __attribute__((ext_vector_type(4)));
typedef bf16_t bf16x8 __attribute__((ext_vector_type(8)));
typedef float  f32x4  __attribute__((ext_vector_type(4)));

// ---------------- K0: fold weights ----------------
// A[c][d]  = sum_e Wq[e][c]*Wk[e][d]   (Qt = cur@A + c0; c0 = bq@Wk)
// W2[e][d] = sum_k Wo[e][k]*Wv[k][d]   (x = cur + p@W2^T + b2; b2 = Wo@bv + bo)
// bk dropped: adds Q.bk uniformly to logits -> softmax-invariant.
__global__ void fold_w(const float* __restrict__ Wq, const float* __restrict__ bq,
                       const float* __restrict__ Wk,
                       const float* __restrict__ Wv, const float* __restrict__ bv,
                       const float* __restrict__ Wo, const float* __restrict__ bo,
                       bf16_t* __restrict__ Atb, bf16_t* __restrict__ W2b,
                       float* __restrict__ c0, float* __restrict__ b2) {
  int i = blockIdx.x * 256 + threadIdx.x;   // 0..16383
  int d = i & 127;
  int c = i >> 7;                            // doubles as 'e' for W2
  float accA = 0.f, accW = 0.f;
  for (int e = 0; e < 128; ++e) {
    accA += Wq[e*128 + c] * Wk[e*128 + d];
    accW += Wo[c*128 + e] * Wv[e*128 + d];
  }
  Atb[d*128 + c] = (bf16_t)accA;
  W2b[c*128 + d] = (bf16_t)accW;
  if (i < 128) {
    float s0 = 0.f, s1 = 0.f;
    for (int e = 0; e < 128; ++e) {
      s0 += bq[e] * Wk[e*128 + i];
      s1 += Wo[i*128 + e] * bv[e];
    }
    c0[i] = s0;
    b2[i] = s1 + bo[i];
  }
}

// ---------------- K1: Qt = cur @ A + c0  (bf16 MFMA) ----------------
__global__ __launch_bounds__(256) void gemm_qt(
    const float* __restrict__ cur, const bf16_t* __restrict__ Atb,
    const float* __restrict__ c0, bf16_t* __restrict__ Qtb) {
  __shared__ bf16_t At[128][132];
  __shared__ bf16_t Cu[64][132];
  const int t = threadIdx.x;
  const int r0 = blockIdx.x * 64;
  #pragma unroll
  for (int s0 = 0; s0 < 2048; s0 += 256) {         // stage A^T
    int s = s0 + t;
    int d = s >> 4, cc = (s & 15) * 8;
    bf16x8 v = *(const bf16x8*)(Atb + d*128 + cc);
    *(bf16x4*)&At[d][cc]     = __builtin_shufflevector(v, v, 0,1,2,3);
    *(bf16x4*)&At[d][cc + 4] = __builtin_shufflevector(v, v, 4,5,6,7);
  }
  #pragma unroll
  for (int s0 = 0; s0 < 2048; s0 += 256) {         // stage cur tile -> bf16
    int s = s0 + t;
    int r = s >> 5, cc = (s & 31) * 4;
    f32x4 v = *(const f32x4*)(cur + (size_t)(r0 + r)*128 + cc);
    bf16x4 b;
    b[0] = (bf16_t)v[0]; b[1] = (bf16_t)v[1]; b[2] = (bf16_t)v[2]; b[3] = (bf16_t)v[3];
    *(bf16x4*)&Cu[r][cc] = b;
  }
  __syncthreads();
  const int w = t >> 6, l = t & 63;
  const int lr = l & 15, lg = l >> 4;
  f32x4 acc[8] = {};
  #pragma unroll
  for (int ks = 0; ks < 4; ++ks) {
    const int kb = ks*32 + lg*4;
    bf16x4 alo = *(const bf16x4*)&Cu[w*16 + lr][kb];
    bf16x4 ahi = *(const bf16x4*)&Cu[w*16 + lr][kb + 16];
    bf16x8 a = __builtin_shufflevector(alo, ahi, 0,1,2,3,4,5,6,7);
    #pragma unroll
    for (int n = 0; n < 8; ++n) {
      bf16x4 blo = *(const bf16x4*)&At[n*16 + lr][kb];
      bf16x4 bhi = *(const bf16x4*)&At[n*16 + lr][kb + 16];
      bf16x8 bb = __builtin_shufflevector(blo, bhi, 0,1,2,3,4,5,6,7);
      acc[n] = __builtin_amdgcn_mfma_f32_16x16x32_bf16(a, bb, acc[n], 0, 0, 0);
    }
  }
  #pragma unroll
  for (int n = 0; n < 8; ++n) {                    // C/D: col=lane&15, row=4*(l>>4)+r
    const int col = n*16 + lr;
    const float cv = c0[col];
    #pragma unroll
    for (int r = 0; r < 4; ++r) {
      const int row = r0 + w*16 + lg*4 + r;
      Qtb[(size_t)row*128 + col] = (bf16_t)(acc[n][r] + cv);
    }
  }
}

// ---------------- K2: fused attention + GEMM2 + LayerNorm ----------------
// Block = 256 thr (4 waves) handles 64 rows. Phase A: wave w gathers+attends
// rows [r0+16w, +16), writing p rows (bf16) to LDS Pt. Coalesced gather:
// instruction i covers contiguous floats [i*256, (i+1)*256) of the 1024-float
// bank row; lane l holds e = i*256 + 4l + j -> slot m = 2i + (l>>5),
// col d = 4(l&31)+j. Softmax reduces over 32-lane halves. 2-row prefetch
// pipeline hides gather latency. Phase B: MFMA p@W2^T + residual + LN.
__global__ __launch_bounds__(256) void attn_fused(
    const int* __restrict__ idx, const float* __restrict__ bank,
    const bf16_t* __restrict__ Qtb, const bf16_t* __restrict__ W2b,
    const float* __restrict__ b2v, const float* __restrict__ cur,
    const float* __restrict__ gamma, const float* __restrict__ beta,
    float* __restrict__ out) {
  __shared__ bf16_t Wt[128][132];   // W2[e][d], k=d contiguous
  __shared__ bf16_t Pt[64][132];    // p rows
  const int t = threadIdx.x;
  const int r0 = blockIdx.x * 64;
  #pragma unroll
  for (int s0 = 0; s0 < 2048; s0 += 256) {         // stage W2
    int s = s0 + t;
    int e = s >> 4, dd = (s & 15) * 8;
    bf16x8 v = *(const bf16x8*)(W2b + e*128 + dd);
    *(bf16x4*)&Wt[e][dd]     = __builtin_shufflevector(v, v, 0,1,2,3);
    *(bf16x4*)&Wt[e][dd + 4] = __builtin_shufflevector(v, v, 4,5,6,7);
  }

  const int w = t >> 6, l = t & 63;
  const int h = l >> 5, c = l & 31;
  const int nbase = r0 + w*16;

#define LOADROW(n, X0, X1, X2, X3, qx)                                   \
  {                                                                      \
    const float* _p = bank + (size_t)idx[(n)] * 1024 + l*4;              \
    X0 = *(const f32x4*)(_p);                                            \
    X1 = *(const f32x4*)(_p + 256);                                      \
    X2 = *(const f32x4*)(_p + 512);                                      \
    X3 = *(const f32x4*)(_p + 768);                                      \
    bf16x4 _q = *(const bf16x4*)(Qtb + (size_t)(n)*128 + c*4);           \
    qx##0 = (float)_q[0]; qx##1 = (float)_q[1];                          \
    qx##2 = (float)_q[2]; qx##3 = (float)_q[3];                          \
  }

#define COMPUTE(rr, X0, X1, X2, X3, qx)                                  \
  {                                                                      \
    float ps0 = X0[0]*qx##0 + X0[1]*qx##1 + X0[2]*qx##2 + X0[3]*qx##3;   \
    float ps1 = X1[0]*qx##0 + X1[1]*qx##1 + X1[2]*qx##2 + X1[3]*qx##3;   \
    float ps2 = X2[0]*qx##0 + X2[1]*qx##1 + X2[2]*qx##2 + X2[3]*qx##3;   \
    float ps3 = X3[0]*qx##0 + X3[1]*qx##1 + X3[2]*qx##2 + X3[3]*qx##3;   \
    ps0 += __shfl_xor(ps0, 1);  ps1 += __shfl_xor(ps1, 1);               \
    ps2 += __shfl_xor(ps2, 1);  ps3 += __shfl_xor(ps3, 1);               \
    ps0 += __shfl_xor(ps0, 2);  ps1 += __shfl_xor(ps1, 2);               \
    ps2 += __shfl_xor(ps2, 2);  ps3 += __shfl_xor(ps3, 2);               \
    ps0 += __shfl_xor(ps0, 4);  ps1 += __shfl_xor(ps1, 4);               \
    ps2 += __shfl_xor(ps2, 4);  ps3 += __shfl_xor(ps3, 4);               \
    ps0 += __shfl_xor(ps0, 8);  ps1 += __shfl_xor(ps1, 8);               \
    ps2 += __shfl_xor(ps2, 8);  ps3 += __shfl_xor(ps3, 8);               \
    ps0 += __shfl_xor(ps0, 16); ps1 += __shfl_xor(ps1, 16);              \
    ps2 += __shfl_xor(ps2, 16); ps3 += __shfl_xor(ps3, 16);              \
    ps0 *= QK_SCALE; ps1 *= QK_SCALE; ps2 *= QK_SCALE; ps3 *= QK_SCALE;  \
    float mx = fmaxf(fmaxf(ps0, ps1), fmaxf(ps2, ps3));                  \
    mx = fmaxf(mx, __shfl_xor(mx, 32));                                  \
    float e0 = __expf(ps0 - mx), e1 = __expf(ps1 - mx);                  \
    float e2 = __expf(ps2 - mx), e3 = __expf(ps3 - mx);                  \
    float den = e0 + e1 + e2 + e3;                                       \
    den += __shfl_xor(den, 32);                                          \
    const float inv = 1.f / den;                                         \
    e0 *= inv; e1 *= inv; e2 *= inv; e3 *= inv;                          \
    float o0 = e0*X0[0] + e1*X1[0] + e2*X2[0] + e3*X3[0];                \
    float o1 = e0*X0[1] + e1*X1[1] + e2*X2[1] + e3*X3[1];                \
    float o2 = e0*X0[2] + e1*X1[2] + e2*X2[2] + e3*X3[2];                \
    float o3 = e0*X0[3] + e1*X1[3] + e2*X2[3] + e3*X3[3];                \
    o0 += __shfl_xor(o0, 32); o1 += __shfl_xor(o1, 32);                  \
    o2 += __shfl_xor(o2, 32); o3 += __shfl_xor(o3, 32);                  \
    if (h == 0) {                                                        \
      bf16x4 ob;                                                         \
      ob[0] = (bf16_t)o0; ob[1] = (bf16_t)o1;                            \
      ob[2] = (bf16_t)o2; ob[3] = (bf16_t)o3;                            \
      *(bf16x4*)&Pt[w*16 + (rr)][c*4] = ob;                              \
    }                                                                    \
  }

  f32x4 A0, A1, A2, A3, B0, B1, B2, B3;
  float qA0, qA1, qA2, qA3, qB0, qB1, qB2, qB3;
  LOADROW(nbase, A0, A1, A2, A3, qA);
  #pragma unroll
  for (int r = 0; r < 16; r += 2) {
    LOADROW(nbase + r + 1, B0, B1, B2, B3, qB);
    COMPUTE(r, A0, A1, A2, A3, qA);
    const int np = nbase + ((r + 2 < 16) ? r + 2 : r);   // tail: L1-hot dummy
    LOADROW(np, A0, A1, A2, A3, qA);
    COMPUTE(r + 1, B0, B1, B2, B3, qB);
  }
#undef LOADROW
#undef COMPUTE

  __syncthreads();

  // ---- Phase B: x = p @ W2^T + b2 + cur; LayerNorm ----
  const int lr = l & 15, lg = l >> 4;
  f32x4 acc[8] = {};
  #pragma unroll
  for (int ks = 0; ks < 4; ++ks) {
    const int kb = ks*32 + lg*4;
    bf16x4 alo = *(const bf16x4*)&Pt[w*16 + lr][kb];
    bf16x4 ahi = *(const bf16x4*)&Pt[w*16 + lr][kb + 16];
    bf16x8 a = __builtin_shufflevector(alo, ahi, 0,1,2,3,4,5,6,7);
    #pragma unroll
    for (int n = 0; n < 8; ++n) {
      bf16x4 blo = *(const bf16x4*)&Wt[n*16 + lr][kb];
      bf16x4 bhi = *(const bf16x4*)&Wt[n*16 + lr][kb + 16];
      bf16x8 bb = __builtin_shufflevector(blo, bhi, 0,1,2,3,4,5,6,7);
      acc[n] = __builtin_amdgcn_mfma_f32_16x16x32_bf16(a, bb, acc[n], 0, 0, 0);
    }
  }
  float x[8][4];
  #pragma unroll
  for (int n = 0; n < 8; ++n) {
    const int col = n*16 + lr;
    const float bb2 = b2v[col];
    #pragma unroll
    for (int r = 0; r < 4; ++r) {
      const int row = r0 + w*16 + lg*4 + r;
      x[n][r] = acc[n][r] + bb2 + cur[(size_t)row*128 + col];
    }
  }
  #pragma unroll
  for (int r = 0; r < 4; ++r) {
    float s1 = 0.f, s2 = 0.f;
    #pragma unroll
    for (int n = 0; n < 8; ++n) { s1 += x[n][r]; s2 += x[n][r]*x[n][r]; }
    s1 += __shfl_xor(s1, 1); s2 += __shfl_xor(s2, 1);
    s1 += __shfl_xor(s1, 2); s2 += __shfl_xor(s2, 2);
    s1 += __shfl_xor(s1, 4); s2 += __shfl_xor(s2, 4);
    s1 += __shfl_xor(s1, 8); s2 += __shfl_xor(s2, 8);
    const float mean = s1 * (1.f/128.f);
    const float var  = s2 * (1.f/128.f) - mean*mean;
    const float rstd = rsqrtf(var + LN_EPS);
    const int row = r0 + w*16 + lg*4 + r;
    #pragma unroll
    for (int n = 0; n < 8; ++n) {
      const int col = n*16 + lr;
      out[(size_t)row*128 + col] = (x[n][r] - mean)*rstd*gamma[col] + beta[col];
    }
  }
}

extern "C" void kernel_launch(void* const* d_in, const int* in_sizes, int n_in,
                              void* d_out, int out_size, void* d_ws, size_t ws_size,
                              hipStream_t stream) {
  const int*   idx  = (const int*)d_in[0];
  const float* cur  = (const float*)d_in[1];
  const float* bank = (const float*)d_in[2];
  const float* Wq   = (const float*)d_in[3];
  const float* bq   = (const float*)d_in[4];
  const float* Wk   = (const float*)d_in[5];
  // d_in[6] = bk: softmax-invariant, intentionally unused
  const float* Wv   = (const float*)d_in[7];
  const float* bv   = (const float*)d_in[8];
  const float* Wo   = (const float*)d_in[9];
  const float* bo   = (const float*)d_in[10];
  const float* gm   = (const float*)d_in[11];
  const float* bt   = (const float*)d_in[12];
  float* out = (float*)d_out;

  char* ws = (char*)d_ws;
  bf16_t* Atb = (bf16_t*)(ws);                    // 32 KB
  bf16_t* W2b = (bf16_t*)(ws + 32768);            // 32 KB
  float*  c0  = (float*)(ws + 65536);             // 512 B
  float*  b2  = (float*)(ws + 65536 + 512);       // 512 B
  bf16_t* Qtb = (bf16_t*)(ws + (1 << 20));        // 16 MB

  fold_w<<<64, 256, 0, stream>>>(Wq, bq, Wk, Wv, bv, Wo, bo, Atb, W2b, c0, b2);
  gemm_qt<<<NREADS/64, 256, 0, stream>>>(cur, Atb, c0, Qtb);
  attn_fused<<<NREADS/64, 256, 0, stream>>>(idx, bank, Qtb, W2b, b2, cur, gm, bt, out);
}

// Round 9
// 564.311 us; speedup vs baseline: 1.0242x; 1.0110x over previous
//
#include <hip/hip_runtime.h>
#include <hip/hip_bf16.h>
#include <cstddef>
#include <cstdint>

#define NREADS 65536
#define DDIM 128
#define BANKM 8
#define LN_EPS 1e-5f
#define QK_SCALE 0.08838834764831845f

typedef __bf16 bf16_t;
typedef bf16_t bf16x4 __attribute__((ext_vector_type(4)));
typedef bf16_t bf16x8 __attribute__((ext_vector_type(8)));
typedef float  f32x4  __attribute__((ext_vector_type(4)));

// ---------------- K0: fold weights ----------------
// A[c][d]  = sum_e Wq[e][c]*Wk[e][d]   (Q = cur@A + c0; c0 = bq@Wk)
// W2[e][d] = sum_k Wo[e][k]*Wv[k][d]   (x = cur + p@W2^T + b2; b2 = Wo@bv + bo)
// bk dropped: adds Q.bk uniformly to logits -> softmax-invariant.
__global__ void fold_w(const float* __restrict__ Wq, const float* __restrict__ bq,
                       const float* __restrict__ Wk,
                       const float* __restrict__ Wv, const float* __restrict__ bv,
                       const float* __restrict__ Wo, const float* __restrict__ bo,
                       bf16_t* __restrict__ Atb, bf16_t* __restrict__ W2b,
                       float* __restrict__ c0, float* __restrict__ b2) {
  int i = blockIdx.x * 256 + threadIdx.x;   // 0..16383
  int d = i & 127;
  int c = i >> 7;                            // doubles as 'e' for W2
  float accA = 0.f, accW = 0.f;
  for (int e = 0; e < 128; ++e) {
    accA += Wq[e*128 + c] * Wk[e*128 + d];
    accW += Wo[c*128 + e] * Wv[e*128 + d];
  }
  Atb[d*128 + c] = (bf16_t)accA;
  W2b[c*128 + d] = (bf16_t)accW;
  if (i < 128) {
    float s0 = 0.f, s1 = 0.f;
    for (int e = 0; e < 128; ++e) {
      s0 += bq[e] * Wk[e*128 + i];
      s1 += Wo[i*128 + e] * bv[e];
    }
    c0[i] = s0;
    b2[i] = s1 + bo[i];
  }
}

// ---------------- K1: fully fused Q-GEMM + attention + O-GEMM + LN ----------
// Block = 256 thr (4 waves) owns 64 rows. LDS phases:
//   Ab: A^T (phase 0 MFMA B-operand)  -> W2 (phase B B-operand)
//   Cu: cur bf16 tile (phase 0 A-op)  -> P rows (phase B A-op)
//   Ql: Q rows bf16 (phase 0 out, phase A in)
// Phase 0: Q = cur@A + c0 via MFMA, write Ql. Phase A: per-wave gather 16
// rows (coalesced: instr i covers contiguous 1KB of the 4KB bank row;
// slot m = 2i + (l>>5), col d = 4(l&31)+j; softmax over 32-lane halves;
// 2-row pipeline). Phase B: x = P@W2^T + b2 + cur (L2-hot re-read); LN.
__global__ __launch_bounds__(256) void mega(
    const int* __restrict__ idx, const float* __restrict__ bank,
    const float* __restrict__ cur,
    const bf16_t* __restrict__ Atb, const float* __restrict__ c0,
    const bf16_t* __restrict__ W2b, const float* __restrict__ b2v,
    const float* __restrict__ gamma, const float* __restrict__ beta,
    float* __restrict__ out) {
  __shared__ bf16_t Ab[128][132];
  __shared__ bf16_t Cu[64][132];
  __shared__ bf16_t Ql[64][132];
  const int t = threadIdx.x;
  const int r0 = blockIdx.x * 64;
  const int w = t >> 6, l = t & 63;
  const int lr = l & 15, lg = l >> 4;
  const int h = l >> 5, c = l & 31;

  // ---- Phase 0: stage A^T + cur; MFMA Q = cur@A + c0 -> Ql ----
  #pragma unroll
  for (int s0 = 0; s0 < 2048; s0 += 256) {
    int s = s0 + t;
    int d = s >> 4, cc = (s & 15) * 8;
    bf16x8 v = *(const bf16x8*)(Atb + d*128 + cc);
    *(bf16x4*)&Ab[d][cc]     = __builtin_shufflevector(v, v, 0,1,2,3);
    *(bf16x4*)&Ab[d][cc + 4] = __builtin_shufflevector(v, v, 4,5,6,7);
  }
  #pragma unroll
  for (int s0 = 0; s0 < 2048; s0 += 256) {
    int s = s0 + t;
    int r = s >> 5, cc = (s & 31) * 4;
    f32x4 v = *(const f32x4*)(cur + (size_t)(r0 + r)*128 + cc);
    bf16x4 b;
    b[0] = (bf16_t)v[0]; b[1] = (bf16_t)v[1]; b[2] = (bf16_t)v[2]; b[3] = (bf16_t)v[3];
    *(bf16x4*)&Cu[r][cc] = b;
  }
  __syncthreads();
  {
    f32x4 acc[8] = {};
    #pragma unroll
    for (int ks = 0; ks < 4; ++ks) {
      const int kb = ks*32 + lg*4;
      bf16x4 alo = *(const bf16x4*)&Cu[w*16 + lr][kb];
      bf16x4 ahi = *(const bf16x4*)&Cu[w*16 + lr][kb + 16];
      bf16x8 a = __builtin_shufflevector(alo, ahi, 0,1,2,3,4,5,6,7);
      #pragma unroll
      for (int n = 0; n < 8; ++n) {
        bf16x4 blo = *(const bf16x4*)&Ab[n*16 + lr][kb];
        bf16x4 bhi = *(const bf16x4*)&Ab[n*16 + lr][kb + 16];
        bf16x8 bb = __builtin_shufflevector(blo, bhi, 0,1,2,3,4,5,6,7);
        acc[n] = __builtin_amdgcn_mfma_f32_16x16x32_bf16(a, bb, acc[n], 0, 0, 0);
      }
    }
    #pragma unroll
    for (int n = 0; n < 8; ++n) {              // C/D: col=lane&15, row=4*lg+r
      const int col = n*16 + lr;
      const float cv = c0[col];
      #pragma unroll
      for (int r = 0; r < 4; ++r)
        Ql[w*16 + lg*4 + r][col] = (bf16_t)(acc[n][r] + cv);
    }
  }
  __syncthreads();

  // ---- stage W2 into Ab (Ab's A^T content is dead; readers sync'd) ----
  #pragma unroll
  for (int s0 = 0; s0 < 2048; s0 += 256) {
    int s = s0 + t;
    int e = s >> 4, dd = (s & 15) * 8;
    bf16x8 v = *(const bf16x8*)(W2b + e*128 + dd);
    *(bf16x4*)&Ab[e][dd]     = __builtin_shufflevector(v, v, 0,1,2,3);
    *(bf16x4*)&Ab[e][dd + 4] = __builtin_shufflevector(v, v, 4,5,6,7);
  }

  // ---- Phase A: gather + attend; P -> Cu (cur tile is dead) ----
#define LOADROW(ln, X0, X1, X2, X3, qx)                                  \
  {                                                                      \
    const float* _p = bank + (size_t)idx[r0 + (ln)] * 1024 + l*4;        \
    X0 = *(const f32x4*)(_p);                                            \
    X1 = *(const f32x4*)(_p + 256);                                      \
    X2 = *(const f32x4*)(_p + 512);                                      \
    X3 = *(const f32x4*)(_p + 768);                                      \
    bf16x4 _q = *(const bf16x4*)&Ql[(ln)][c*4];                          \
    qx##0 = (float)_q[0]; qx##1 = (float)_q[1];                          \
    qx##2 = (float)_q[2]; qx##3 = (float)_q[3];                          \
  }

#define COMPUTE(rr, X0, X1, X2, X3, qx)                                  \
  {                                                                      \
    float ps0 = X0[0]*qx##0 + X0[1]*qx##1 + X0[2]*qx##2 + X0[3]*qx##3;   \
    float ps1 = X1[0]*qx##0 + X1[1]*qx##1 + X1[2]*qx##2 + X1[3]*qx##3;   \
    float ps2 = X2[0]*qx##0 + X2[1]*qx##1 + X2[2]*qx##2 + X2[3]*qx##3;   \
    float ps3 = X3[0]*qx##0 + X3[1]*qx##1 + X3[2]*qx##2 + X3[3]*qx##3;   \
    ps0 += __shfl_xor(ps0, 1);  ps1 += __shfl_xor(ps1, 1);               \
    ps2 += __shfl_xor(ps2, 1);  ps3 += __shfl_xor(ps3, 1);               \
    ps0 += __shfl_xor(ps0, 2);  ps1 += __shfl_xor(ps1, 2);               \
    ps2 += __shfl_xor(ps2, 2);  ps3 += __shfl_xor(ps3, 2);               \
    ps0 += __shfl_xor(ps0, 4);  ps1 += __shfl_xor(ps1, 4);               \
    ps2 += __shfl_xor(ps2, 4);  ps3 += __shfl_xor(ps3, 4);               \
    ps0 += __shfl_xor(ps0, 8);  ps1 += __shfl_xor(ps1, 8);               \
    ps2 += __shfl_xor(ps2, 8);  ps3 += __shfl_xor(ps3, 8);               \
    ps0 += __shfl_xor(ps0, 16); ps1 += __shfl_xor(ps1, 16);              \
    ps2 += __shfl_xor(ps2, 16); ps3 += __shfl_xor(ps3, 16);              \
    ps0 *= QK_SCALE; ps1 *= QK_SCALE; ps2 *= QK_SCALE; ps3 *= QK_SCALE;  \
    float mx = fmaxf(fmaxf(ps0, ps1), fmaxf(ps2, ps3));                  \
    mx = fmaxf(mx, __shfl_xor(mx, 32));                                  \
    float e0 = __expf(ps0 - mx), e1 = __expf(ps1 - mx);                  \
    float e2 = __expf(ps2 - mx), e3 = __expf(ps3 - mx);                  \
    float den = e0 + e1 + e2 + e3;                                       \
    den += __shfl_xor(den, 32);                                          \
    const float inv = 1.f / den;                                         \
    e0 *= inv; e1 *= inv; e2 *= inv; e3 *= inv;                          \
    float o0 = e0*X0[0] + e1*X1[0] + e2*X2[0] + e3*X3[0];                \
    float o1 = e0*X0[1] + e1*X1[1] + e2*X2[1] + e3*X3[1];                \
    float o2 = e0*X0[2] + e1*X1[2] + e2*X2[2] + e3*X3[2];                \
    float o3 = e0*X0[3] + e1*X1[3] + e2*X2[3] + e3*X3[3];                \
    o0 += __shfl_xor(o0, 32); o1 += __shfl_xor(o1, 32);                  \
    o2 += __shfl_xor(o2, 32); o3 += __shfl_xor(o3, 32);                  \
    if (h == 0) {                                                        \
      bf16x4 ob;                                                         \
      ob[0] = (bf16_t)o0; ob[1] = (bf16_t)o1;                            \
      ob[2] = (bf16_t)o2; ob[3] = (bf16_t)o3;                            \
      *(bf16x4*)&Cu[w*16 + (rr)][c*4] = ob;                              \
    }                                                                    \
  }

  {
    f32x4 A0, A1, A2, A3, B0, B1, B2, B3;
    float qA0, qA1, qA2, qA3, qB0, qB1, qB2, qB3;
    const int lb = w*16;
    LOADROW(lb, A0, A1, A2, A3, qA);
    #pragma unroll
    for (int r = 0; r < 16; r += 2) {
      LOADROW(lb + r + 1, B0, B1, B2, B3, qB);
      COMPUTE(r, A0, A1, A2, A3, qA);
      const int np = lb + ((r + 2 < 16) ? r + 2 : r);   // tail: L1-hot dummy
      LOADROW(np, A0, A1, A2, A3, qA);
      COMPUTE(r + 1, B0, B1, B2, B3, qB);
    }
  }
#undef LOADROW
#undef COMPUTE

  __syncthreads();

  // ---- Phase B: x = P @ W2^T + b2 + cur; LayerNorm -> out ----
  f32x4 acc[8] = {};
  #pragma unroll
  for (int ks = 0; ks < 4; ++ks) {
    const int kb = ks*32 + lg*4;
    bf16x4 alo = *(const bf16x4*)&Cu[w*16 + lr][kb];
    bf16x4 ahi = *(const bf16x4*)&Cu[w*16 + lr][kb + 16];
    bf16x8 a = __builtin_shufflevector(alo, ahi, 0,1,2,3,4,5,6,7);
    #pragma unroll
    for (int n = 0; n < 8; ++n) {
      bf16x4 blo = *(const bf16x4*)&Ab[n*16 + lr][kb];
      bf16x4 bhi = *(const bf16x4*)&Ab[n*16 + lr][kb + 16];
      bf16x8 bb = __builtin_shufflevector(blo, bhi, 0,1,2,3,4,5,6,7);
      acc[n] = __builtin_amdgcn_mfma_f32_16x16x32_bf16(a, bb, acc[n], 0, 0, 0);
    }
  }
  float x[8][4];
  #pragma unroll
  for (int n = 0; n < 8; ++n) {
    const int col = n*16 + lr;
    const float bb2 = b2v[col];
    #pragma unroll
    for (int r = 0; r < 4; ++r) {
      const int row = r0 + w*16 + lg*4 + r;
      x[n][r] = acc[n][r] + bb2 + cur[(size_t)row*128 + col];  // L2-hot
    }
  }
  #pragma unroll
  for (int r = 0; r < 4; ++r) {
    float s1 = 0.f, s2 = 0.f;
    #pragma unroll
    for (int n = 0; n < 8; ++n) { s1 += x[n][r]; s2 += x[n][r]*x[n][r]; }
    s1 += __shfl_xor(s1, 1); s2 += __shfl_xor(s2, 1);
    s1 += __shfl_xor(s1, 2); s2 += __shfl_xor(s2, 2);
    s1 += __shfl_xor(s1, 4); s2 += __shfl_xor(s2, 4);
    s1 += __shfl_xor(s1, 8); s2 += __shfl_xor(s2, 8);
    const float mean = s1 * (1.f/128.f);
    const float var  = s2 * (1.f/128.f) - mean*mean;
    const float rstd = rsqrtf(var + LN_EPS);
    const int row = r0 + w*16 + lg*4 + r;
    #pragma unroll
    for (int n = 0; n < 8; ++n) {
      const int col = n*16 + lr;
      out[(size_t)row*128 + col] = (x[n][r] - mean)*rstd*gamma[col] + beta[col];
    }
  }
}

extern "C" void kernel_launch(void* const* d_in, const int* in_sizes, int n_in,
                              void* d_out, int out_size, void* d_ws, size_t ws_size,
                              hipStream_t stream) {
  const int*   idx  = (const int*)d_in[0];
  const float* cur  = (const float*)d_in[1];
  const float* bank = (const float*)d_in[2];
  const float* Wq   = (const float*)d_in[3];
  const float* bq   = (const float*)d_in[4];
  const float* Wk   = (const float*)d_in[5];
  // d_in[6] = bk: softmax-invariant, intentionally unused
  const float* Wv   = (const float*)d_in[7];
  const float* bv   = (const float*)d_in[8];
  const float* Wo   = (const float*)d_in[9];
  const float* bo   = (const float*)d_in[10];
  const float* gm   = (const float*)d_in[11];
  const float* bt   = (const float*)d_in[12];
  float* out = (float*)d_out;

  char* ws = (char*)d_ws;
  bf16_t* Atb = (bf16_t*)(ws);                    // 32 KB
  bf16_t* W2b = (bf16_t*)(ws + 32768);            // 32 KB
  float*  c0  = (float*)(ws + 65536);             // 512 B
  float*  b2  = (float*)(ws + 65536 + 512);       // 512 B

  fold_w<<<64, 256, 0, stream>>>(Wq, bq, Wk, Wv, bv, Wo, bo, Atb, W2b, c0, b2);
  mega<<<NREADS/64, 256, 0, stream>>>(idx, bank, cur, Atb, c0, W2b, b2, gm, bt, out);
}